// Round 1
// baseline (1868.541 us; speedup 1.0000x reference)
//
#include <hip/hip_runtime.h>
#include <cstddef>
#include <cstdint>

#define B_    8
#define S_    512
#define L_    15
#define D_    768
#define H_    512
#define KTOP  102
#define SL_   (S_ * L_)        // 7680
#define M_    (B_ * SL_)       // 61440

// output float offsets (concatenated return tuple)
#define OFF_SCORES 0
#define OFF_IDX    61440
#define OFF_FVECS  62256
#define OFF_FSC    688944
#define OFF_FBEG   689760
#define OFF_FEND   690576
#define OFF_SLEN   691392
#define OFF_SQ     691400
#define OFF_TRI    774632

__device__ __forceinline__ void fma16(const float4 a, const float b0, const float b1,
                                      const float b2, const float b3, float acc[4][4]) {
  acc[0][0] = fmaf(a.x, b0, acc[0][0]); acc[0][1] = fmaf(a.x, b1, acc[0][1]);
  acc[0][2] = fmaf(a.x, b2, acc[0][2]); acc[0][3] = fmaf(a.x, b3, acc[0][3]);
  acc[1][0] = fmaf(a.y, b0, acc[1][0]); acc[1][1] = fmaf(a.y, b1, acc[1][1]);
  acc[1][2] = fmaf(a.y, b2, acc[1][2]); acc[1][3] = fmaf(a.y, b3, acc[1][3]);
  acc[2][0] = fmaf(a.z, b0, acc[2][0]); acc[2][1] = fmaf(a.z, b1, acc[2][1]);
  acc[2][2] = fmaf(a.z, b2, acc[2][2]); acc[2][3] = fmaf(a.z, b3, acc[2][3]);
  acc[3][0] = fmaf(a.w, b0, acc[3][0]); acc[3][1] = fmaf(a.w, b1, acc[3][1]);
  acc[3][2] = fmaf(a.w, b2, acc[3][2]); acc[3][3] = fmaf(a.w, b3, acc[3][3]);
}

// Fused 3-layer MLP scorer: 32 spans per block.
// h1 kept transposed+swizzled in LDS ([k][m]); h2 fused directly into w3 dot.
__global__ __launch_bounds__(256, 2)
void fused_mlp_kernel(const float* __restrict__ V,     // [M, 768]
                      const float* __restrict__ mask,  // [M]
                      const float* __restrict__ W1, const float* __restrict__ B1,
                      const float* __restrict__ W2, const float* __restrict__ B2,
                      const float* __restrict__ W3, const float* __restrict__ B3,
                      float* __restrict__ out_scores)  // [M]
{
  __shared__ float h1t[H_][32];     // 64 KB, logical [k][m], m-groups XOR-swizzled by k
  __shared__ float As_t[16][32];    // V tile transposed [k][m]
  __shared__ float Bs[16][128];     // weight tile [k][n]
  __shared__ float scoreS[32];

  const int t  = threadIdx.x;
  const int tx = t & 31;            // col thread (n = n0 + tx + 32j)
  const int ty = t >> 5;            // row thread (m = ty*4 + i)
  const int m0 = blockIdx.x * 32;

  if (t < 32) scoreS[t] = 0.0f;

  // ---------------- Layer 1: h1 = relu(V @ W1 + b1) ----------------
  for (int n0 = 0; n0 < H_; n0 += 128) {
    float acc[4][4] = {};
    for (int k0 = 0; k0 < D_; k0 += 16) {
      { // stage V tile (transposed into LDS)
        int r = t >> 3;            // 0..31 span row
        int c = (t & 7) * 2;       // 0..14 k col
        float2 v = *reinterpret_cast<const float2*>(&V[(size_t)(m0 + r) * D_ + k0 + c]);
        As_t[c][r]     = v.x;
        As_t[c + 1][r] = v.y;
      }
      { // stage W1 tile
        int r = t >> 4;            // 0..15
        int c = (t & 15) * 8;      // 0..120
        const float4* src = reinterpret_cast<const float4*>(&W1[(size_t)(k0 + r) * H_ + n0 + c]);
        *reinterpret_cast<float4*>(&Bs[r][c])     = src[0];
        *reinterpret_cast<float4*>(&Bs[r][c + 4]) = src[1];
      }
      __syncthreads();
      #pragma unroll
      for (int kk = 0; kk < 16; ++kk) {
        float4 a = *reinterpret_cast<const float4*>(&As_t[kk][ty * 4]);
        float b0 = Bs[kk][tx], b1 = Bs[kk][tx + 32], b2 = Bs[kk][tx + 64], b3 = Bs[kk][tx + 96];
        fma16(a, b0, b1, b2, b3, acc);
      }
      __syncthreads();
    }
    #pragma unroll
    for (int j = 0; j < 4; ++j) {
      int n = n0 + tx + 32 * j;
      float bb = B1[n];
      float4 hv;
      hv.x = fmaxf(acc[0][j] + bb, 0.0f);
      hv.y = fmaxf(acc[1][j] + bb, 0.0f);
      hv.z = fmaxf(acc[2][j] + bb, 0.0f);
      hv.w = fmaxf(acc[3][j] + bb, 0.0f);
      *reinterpret_cast<float4*>(&h1t[n][4 * ((ty + n) & 7)]) = hv;
    }
  }
  __syncthreads();

  // ------------- Layer 2 + 3: score = relu(h1 @ W2 + b2) . w3 -------------
  float spart[4] = {0.0f, 0.0f, 0.0f, 0.0f};
  for (int n0 = 0; n0 < H_; n0 += 128) {
    float acc[4][4] = {};
    for (int k0 = 0; k0 < H_; k0 += 16) {
      { // stage W2 tile
        int r = t >> 4;
        int c = (t & 15) * 8;
        const float4* src = reinterpret_cast<const float4*>(&W2[(size_t)(k0 + r) * H_ + n0 + c]);
        *reinterpret_cast<float4*>(&Bs[r][c])     = src[0];
        *reinterpret_cast<float4*>(&Bs[r][c + 4]) = src[1];
      }
      __syncthreads();
      #pragma unroll
      for (int kk = 0; kk < 16; ++kk) {
        int k = k0 + kk;
        float4 a = *reinterpret_cast<const float4*>(&h1t[k][4 * ((ty + k) & 7)]);
        float b0 = Bs[kk][tx], b1 = Bs[kk][tx + 32], b2 = Bs[kk][tx + 64], b3 = Bs[kk][tx + 96];
        fma16(a, b0, b1, b2, b3, acc);
      }
      __syncthreads();
    }
    #pragma unroll
    for (int j = 0; j < 4; ++j) {
      int n = n0 + tx + 32 * j;
      float bb = B2[n];
      float w3v = W3[n];
      spart[0] = fmaf(fmaxf(acc[0][j] + bb, 0.0f), w3v, spart[0]);
      spart[1] = fmaf(fmaxf(acc[1][j] + bb, 0.0f), w3v, spart[1]);
      spart[2] = fmaf(fmaxf(acc[2][j] + bb, 0.0f), w3v, spart[2]);
      spart[3] = fmaf(fmaxf(acc[3][j] + bb, 0.0f), w3v, spart[3]);
    }
  }
  #pragma unroll
  for (int i = 0; i < 4; ++i) atomicAdd(&scoreS[ty * 4 + i], spart[i]);
  __syncthreads();

  if (t < 32) {
    int gm = m0 + t;
    float sc = scoreS[t] + B3[0];
    sc -= (1.0f - mask[gm]) * 10000.0f;
    out_scores[gm] = sc;
  }
}

// Per-batch top-K=102 by iterative argmax (lowest-index tie-break, like lax.top_k),
// then odd-even sort ascending. Also emits span_lengths.
__global__ void topk_kernel(const float* __restrict__ scores,
                            const int* __restrict__ seqlen,
                            float* __restrict__ out,
                            int* __restrict__ ws_idx,
                            int* __restrict__ ws_sl)
{
  __shared__ float vals[SL_];
  __shared__ float rv[4];
  __shared__ int   ri[4];
  __shared__ int   sel[KTOP];

  const int t = threadIdx.x;   // 256
  const int b = blockIdx.x;    // 8
  const float* s = scores + (size_t)b * SL_;

  for (int i = t; i < SL_; i += 256) vals[i] = s[i];
  __syncthreads();

  for (int it = 0; it < KTOP; ++it) {
    float bv = -3.0e38f;
    int   bi = 0x7fffffff;
    for (int i = t; i < SL_; i += 256) {
      float v = vals[i];
      if (v > bv) { bv = v; bi = i; }   // ascending scan -> lowest idx on tie
    }
    #pragma unroll
    for (int off = 32; off > 0; off >>= 1) {
      float ov = __shfl_down(bv, off, 64);
      int   oi = __shfl_down(bi, off, 64);
      if (ov > bv || (ov == bv && oi < bi)) { bv = ov; bi = oi; }
    }
    if ((t & 63) == 0) { rv[t >> 6] = bv; ri[t >> 6] = bi; }
    __syncthreads();
    if (t == 0) {
      float fb = rv[0]; int fi = ri[0];
      #pragma unroll
      for (int w = 1; w < 4; ++w)
        if (rv[w] > fb || (rv[w] == fb && ri[w] < fi)) { fb = rv[w]; fi = ri[w]; }
      sel[it] = fi;
      vals[fi] = -3.0e38f;
    }
    __syncthreads();
  }

  // odd-even transposition sort, ascending
  for (int pass = 0; pass < KTOP; ++pass) {
    int i = 2 * t + (pass & 1);
    if (i + 1 < KTOP) {
      int a = sel[i], c = sel[i + 1];
      if (a > c) { sel[i] = c; sel[i + 1] = a; }
    }
    __syncthreads();
  }

  if (t < KTOP) {
    out[OFF_IDX + b * KTOP + t] = (float)sel[t];
    ws_idx[b * KTOP + t] = sel[t];
  }
  if (t == 0) {
    int len = seqlen[b];
    int v = (int)(0.2f * (float)len);   // replicate f32 mult + trunc
    if (v > KTOP) v = KTOP;
    out[OFF_SLEN + b] = (float)v;
    ws_sl[b] = v;
  }
}

// Gather f_vecs / f_scores / f_begin / f_end through the pruned indices.
__global__ void gather_kernel(const float* __restrict__ V,
                              const int* __restrict__ sbeg,
                              const int* __restrict__ send,
                              float* __restrict__ out,
                              const int* __restrict__ ws_idx)
{
  const int blk = blockIdx.x;          // b*KTOP + k
  const int b   = blk / KTOP;
  const int t   = threadIdx.x;         // 192 threads * float4 = 768
  const int sid = ws_idx[blk];
  const size_t src = ((size_t)b * SL_ + sid) * D_;
  const float4* s4 = reinterpret_cast<const float4*>(V + src);
  float4* d4 = reinterpret_cast<float4*>(out + OFF_FVECS + (size_t)blk * D_);
  d4[t] = s4[t];
  if (t == 0) {
    int gi = b * SL_ + sid;
    out[OFF_FSC  + blk] = out[OFF_SCORES + gi];
    out[OFF_FBEG + blk] = (float)sbeg[gi];
    out[OFF_FEND + blk] = (float)send[gi];
  }
}

__global__ void masks_kernel(float* __restrict__ out, const int* __restrict__ ws_sl)
{
  int e = blockIdx.x * 256 + threadIdx.x;
  if (e >= B_ * KTOP * KTOP) return;
  int b = e / (KTOP * KTOP);
  int r = e - b * (KTOP * KTOP);
  int i = r / KTOP;
  int j = r - i * KTOP;
  int len = ws_sl[b];
  float sq = (i < len && j < len) ? 1.0f : 0.0f;
  out[OFF_SQ  + e] = sq;
  out[OFF_TRI + e] = (j <= i) ? sq : 0.0f;
}

extern "C" void kernel_launch(void* const* d_in, const int* in_sizes, int n_in,
                              void* d_out, int out_size, void* d_ws, size_t ws_size,
                              hipStream_t stream)
{
  const float* V    = (const float*)d_in[0];
  const float* mask = (const float*)d_in[1];
  const int*   sbeg = (const int*)d_in[2];
  const int*   send = (const int*)d_in[3];
  const int*   slen = (const int*)d_in[4];
  const float* W1 = (const float*)d_in[5];
  const float* B1 = (const float*)d_in[6];
  const float* W2 = (const float*)d_in[7];
  const float* B2 = (const float*)d_in[8];
  const float* W3 = (const float*)d_in[9];
  const float* B3 = (const float*)d_in[10];
  float* out = (float*)d_out;
  int* ws_idx = (int*)d_ws;
  int* ws_sl  = ws_idx + B_ * KTOP;

  fused_mlp_kernel<<<M_ / 32, 256, 0, stream>>>(V, mask, W1, B1, W2, B2, W3, B3, out);
  topk_kernel<<<B_, 256, 0, stream>>>(out, slen, out + 0, ws_idx, ws_sl);
  gather_kernel<<<B_ * KTOP, 192, 0, stream>>>(V, sbeg, send, out, ws_idx);
  masks_kernel<<<(B_ * KTOP * KTOP + 255) / 256, 256, 0, stream>>>(out, ws_sl);
}

// Round 3
// 716.392 us; speedup vs baseline: 2.6083x; 2.6083x over previous
//
#include <hip/hip_runtime.h>
#include <cstddef>
#include <cstdint>

#define B_    8
#define S_    512
#define L_    15
#define D_    768
#define H_    512
#define KTOP  102
#define SL_   (S_ * L_)        // 7680
#define M_    (B_ * SL_)       // 61440

// output float offsets (concatenated return tuple)
#define OFF_SCORES 0
#define OFF_IDX    61440
#define OFF_FVECS  62256
#define OFF_FSC    688944
#define OFF_FBEG   689760
#define OFF_FEND   690576
#define OFF_SLEN   691392
#define OFF_SQ     691400
#define OFF_TRI    774632

typedef _Float16 f16;
typedef __attribute__((ext_vector_type(4))) _Float16 f16x4;
typedef __attribute__((ext_vector_type(8))) _Float16 f16x8;
typedef __attribute__((ext_vector_type(16))) float f32x16;

// persistent device scratch (rewritten fully every launch)
__device__ f16   g_W1h[512 * 768], g_W1l[512 * 768];   // W1^T split planes [n][k]
__device__ f16   g_W2h[512 * 512], g_W2l[512 * 512];   // W2^T split planes [n][k]
__device__ f16   g_h1h[(size_t)M_ * H_];               // h1 hi plane [M][512]
__device__ f16   g_h1l[(size_t)M_ * H_];               // h1 lo plane [M][512]
__device__ float g_scores[M_];

__device__ __forceinline__ int swz(int L) { return L ^ (((L >> 9) & 3) << 4); }

__device__ __forceinline__ void gl_lds16(const void* gsrc, void* ldst) {
  __builtin_amdgcn_global_load_lds(
      (const __attribute__((address_space(1))) void*)gsrc,
      (__attribute__((address_space(3))) void*)ldst, 16, 0, 0);
}

__device__ __forceinline__ f16 hi16(float x) { return (f16)x; }
__device__ __forceinline__ f16 lo16(float x) { return (f16)(x - (float)((f16)x)); }

// ---------- prep: split + transpose weights into f16 hi/lo planes ----------
__global__ void prep_kernel(const float* __restrict__ W1, const float* __restrict__ W2) {
  int e = blockIdx.x * 256 + threadIdx.x;
  if (e < 768 * 512) {
    int k = e >> 9, n = e & 511;
    float x = W1[e];
    g_W1h[n * 768 + k] = hi16(x);
    g_W1l[n * 768 + k] = lo16(x);
  } else {
    e -= 768 * 512;
    if (e < 512 * 512) {
      int k = e >> 9, n = e & 511;
      float x = W2[e];
      g_W2h[n * 512 + k] = hi16(x);
      g_W2l[n * 512 + k] = lo16(x);
    }
  }
}

__global__ void init_kernel() {
  g_scores[blockIdx.x * 256 + threadIdx.x] = 0.0f;
}

// ---------- split-f16 MFMA GEMM; LAYER=1: V@W1->h1 planes; LAYER=2: h1@W2 .w3 -> scores ----------
template <int LAYER>
__global__ __launch_bounds__(256, 2)
void gemm_kernel(const float* __restrict__ V,
                 const float* __restrict__ bias,
                 const float* __restrict__ w3) {
  constexpr int K = (LAYER == 1) ? 768 : 512;
  __shared__ __align__(16) char lds[32 * 1024];
  char* Ah = lds;
  char* Al = lds + 8192;
  char* Bh = lds + 16384;
  char* Bl = lds + 24576;

  const int t = threadIdx.x;
  const int lane = t & 63;
  const int w = t >> 6;                  // wave 0..3
  const int wm = w >> 1, wn = w & 1;     // 2x2 wave grid, each 64x64

  // XCD-aware bijective swizzle: 1920 = 8 * 240
  const int o = (blockIdx.x & 7) * 240 + (blockIdx.x >> 3);
  const int nb = o & 3, mb = o >> 2;
  const int m0 = mb * 128, n0 = nb * 128;

  const f16* WH = (LAYER == 1) ? g_W1h : g_W2h;
  const f16* WL = (LAYER == 1) ? g_W1l : g_W2l;

  f32x16 acc[2][2];
  #pragma unroll
  for (int i = 0; i < 2; ++i)
    #pragma unroll
    for (int j = 0; j < 2; ++j) acc[i][j] = (f32x16)0.0f;

  for (int k0 = 0; k0 < K; k0 += 32) {
    // ---- stage B (both planes) via global_load_lds, inverse-swizzled source
    #pragma unroll
    for (int h = 0; h < 2; ++h) {
      int P = (h * 4 + w) * 1024 + lane * 16;
      int Lg = swz(P);
      int r = Lg >> 6, q = (Lg >> 4) & 3;
      size_t go = (size_t)(n0 + r) * K + k0 + q * 8;
      gl_lds16(WH + go, Bh + P);
      gl_lds16(WL + go, Bl + P);
    }
    // ---- stage A
    if (LAYER == 1) {
      // f32 -> split f16, swizzled ds_write
      int row = t >> 1;                  // 0..127
      int ks = (t & 1) * 16;             // 0 or 16
      const float* src = V + (size_t)(m0 + row) * 768 + k0 + ks;
      float4 vv[4];
      vv[0] = *(const float4*)(src);
      vv[1] = *(const float4*)(src + 4);
      vv[2] = *(const float4*)(src + 8);
      vv[3] = *(const float4*)(src + 12);
      #pragma unroll
      for (int j = 0; j < 4; ++j) {
        f16x4 hv, lv;
        hv[0] = hi16(vv[j].x); lv[0] = lo16(vv[j].x);
        hv[1] = hi16(vv[j].y); lv[1] = lo16(vv[j].y);
        hv[2] = hi16(vv[j].z); lv[2] = lo16(vv[j].z);
        hv[3] = hi16(vv[j].w); lv[3] = lo16(vv[j].w);
        int P = swz(row * 64 + (ks + j * 4) * 2);
        *(f16x4*)(Ah + P) = hv;
        *(f16x4*)(Al + P) = lv;
      }
    } else {
      // h1 f16 planes via global_load_lds
      #pragma unroll
      for (int h = 0; h < 2; ++h) {
        int P = (h * 4 + w) * 1024 + lane * 16;
        int Lg = swz(P);
        int r = Lg >> 6, q = (Lg >> 4) & 3;
        size_t go = (size_t)(m0 + r) * 512 + k0 + q * 8;
        gl_lds16(g_h1h + go, Ah + P);
        gl_lds16(g_h1l + go, Al + P);
      }
    }
    __syncthreads();
    // ---- compute: 2 ksteps of 32x32x16, 3 split-products each
    #pragma unroll
    for (int kk = 0; kk < 2; ++kk) {
      const int intra = kk * 32 + (lane >> 5) * 16;
      f16x8 ah[2], al[2], bh[2], bl[2];
      #pragma unroll
      for (int mt = 0; mt < 2; ++mt) {
        int P = swz((wm * 64 + mt * 32 + (lane & 31)) * 64 + intra);
        ah[mt] = *(const f16x8*)(Ah + P);
        al[mt] = *(const f16x8*)(Al + P);
      }
      #pragma unroll
      for (int nt = 0; nt < 2; ++nt) {
        int P = swz((wn * 64 + nt * 32 + (lane & 31)) * 64 + intra);
        bh[nt] = *(const f16x8*)(Bh + P);
        bl[nt] = *(const f16x8*)(Bl + P);
      }
      #pragma unroll
      for (int mt = 0; mt < 2; ++mt)
        #pragma unroll
        for (int nt = 0; nt < 2; ++nt) {
          acc[mt][nt] = __builtin_amdgcn_mfma_f32_32x32x16_f16(ah[mt], bh[nt], acc[mt][nt], 0, 0, 0);
          acc[mt][nt] = __builtin_amdgcn_mfma_f32_32x32x16_f16(al[mt], bh[nt], acc[mt][nt], 0, 0, 0);
          acc[mt][nt] = __builtin_amdgcn_mfma_f32_32x32x16_f16(ah[mt], bl[nt], acc[mt][nt], 0, 0, 0);
        }
    }
    __syncthreads();
  }

  // ---- epilogue
  const int half = lane >> 5;
  if (LAYER == 1) {
    #pragma unroll
    for (int mt = 0; mt < 2; ++mt)
      #pragma unroll
      for (int nt = 0; nt < 2; ++nt) {
        int col = n0 + wn * 64 + nt * 32 + (lane & 31);
        float bb = bias[col];
        #pragma unroll
        for (int r = 0; r < 16; ++r) {
          int m = m0 + wm * 64 + mt * 32 + (r & 3) + ((r >> 2) << 3) + (half << 2);
          float v = fmaxf(acc[mt][nt][r] + bb, 0.0f);
          g_h1h[(size_t)m * 512 + col] = hi16(v);
          g_h1l[(size_t)m * 512 + col] = lo16(v);
        }
      }
  } else {
    #pragma unroll
    for (int mt = 0; mt < 2; ++mt) {
      float s[16];
      #pragma unroll
      for (int r = 0; r < 16; ++r) s[r] = 0.0f;
      #pragma unroll
      for (int nt = 0; nt < 2; ++nt) {
        int col = n0 + wn * 64 + nt * 32 + (lane & 31);
        float bb = bias[col];
        float wv = w3[col];
        #pragma unroll
        for (int r = 0; r < 16; ++r)
          s[r] += fmaxf(acc[mt][nt][r] + bb, 0.0f) * wv;
      }
      #pragma unroll
      for (int off = 1; off < 32; off <<= 1)
        #pragma unroll
        for (int r = 0; r < 16; ++r) s[r] += __shfl_xor(s[r], off, 64);
      if ((lane & 31) == 0) {
        #pragma unroll
        for (int r = 0; r < 16; ++r) {
          int m = m0 + wm * 64 + mt * 32 + (r & 3) + ((r >> 2) << 3) + (half << 2);
          atomicAdd(&g_scores[m], s[r]);
        }
      }
    }
  }
}

// ---------- finalize: bias3 + mask penalty -> out scores ----------
__global__ void finalize_kernel(const float* __restrict__ mask, const float* __restrict__ B3,
                                float* __restrict__ out) {
  int i = blockIdx.x * 256 + threadIdx.x;
  out[OFF_SCORES + i] = g_scores[i] + B3[0] - (1.0f - mask[i]) * 10000.0f;
}

// ---------- top-k / gather / masks (validated in round 1) ----------
__global__ void topk_kernel(const float* __restrict__ scores,
                            const int* __restrict__ seqlen,
                            float* __restrict__ out,
                            int* __restrict__ ws_idx,
                            int* __restrict__ ws_sl) {
  __shared__ float vals[SL_];
  __shared__ float rv[4];
  __shared__ int ri[4];
  __shared__ int sel[KTOP];

  const int t = threadIdx.x;
  const int b = blockIdx.x;
  const float* s = scores + (size_t)b * SL_;

  for (int i = t; i < SL_; i += 256) vals[i] = s[i];
  __syncthreads();

  for (int it = 0; it < KTOP; ++it) {
    float bv = -3.0e38f;
    int bi = 0x7fffffff;
    for (int i = t; i < SL_; i += 256) {
      float v = vals[i];
      if (v > bv) { bv = v; bi = i; }
    }
    #pragma unroll
    for (int off = 32; off > 0; off >>= 1) {
      float ov = __shfl_down(bv, off, 64);
      int oi = __shfl_down(bi, off, 64);
      if (ov > bv || (ov == bv && oi < bi)) { bv = ov; bi = oi; }
    }
    if ((t & 63) == 0) { rv[t >> 6] = bv; ri[t >> 6] = bi; }
    __syncthreads();
    if (t == 0) {
      float fb = rv[0]; int fi = ri[0];
      #pragma unroll
      for (int wv = 1; wv < 4; ++wv)
        if (rv[wv] > fb || (rv[wv] == fb && ri[wv] < fi)) { fb = rv[wv]; fi = ri[wv]; }
      sel[it] = fi;
      vals[fi] = -3.0e38f;
    }
    __syncthreads();
  }

  for (int pass = 0; pass < KTOP; ++pass) {
    int i = 2 * t + (pass & 1);
    if (i + 1 < KTOP) {
      int a = sel[i], c = sel[i + 1];
      if (a > c) { sel[i] = c; sel[i + 1] = a; }
    }
    __syncthreads();
  }

  if (t < KTOP) {
    out[OFF_IDX + b * KTOP + t] = (float)sel[t];
    ws_idx[b * KTOP + t] = sel[t];
  }
  if (t == 0) {
    int len = seqlen[b];
    int v = (int)(0.2f * (float)len);
    if (v > KTOP) v = KTOP;
    out[OFF_SLEN + b] = (float)v;
    ws_sl[b] = v;
  }
}

__global__ void gather_kernel(const float* __restrict__ V,
                              const int* __restrict__ sbeg,
                              const int* __restrict__ send,
                              float* __restrict__ out,
                              const int* __restrict__ ws_idx) {
  const int blk = blockIdx.x;
  const int b = blk / KTOP;
  const int t = threadIdx.x;
  const int sid = ws_idx[blk];
  const float4* s4 = reinterpret_cast<const float4*>(V + ((size_t)b * SL_ + sid) * D_);
  float4* d4 = reinterpret_cast<float4*>(out + OFF_FVECS + (size_t)blk * D_);
  d4[t] = s4[t];
  if (t == 0) {
    int gi = b * SL_ + sid;
    out[OFF_FSC + blk] = out[OFF_SCORES + gi];
    out[OFF_FBEG + blk] = (float)sbeg[gi];
    out[OFF_FEND + blk] = (float)send[gi];
  }
}

__global__ void masks_kernel(float* __restrict__ out, const int* __restrict__ ws_sl) {
  int e = blockIdx.x * 256 + threadIdx.x;
  if (e >= B_ * KTOP * KTOP) return;
  int b = e / (KTOP * KTOP);
  int r = e - b * (KTOP * KTOP);
  int i = r / KTOP;
  int j = r - i * KTOP;
  int len = ws_sl[b];
  float sq = (i < len && j < len) ? 1.0f : 0.0f;
  out[OFF_SQ + e] = sq;
  out[OFF_TRI + e] = (j <= i) ? sq : 0.0f;
}

extern "C" void kernel_launch(void* const* d_in, const int* in_sizes, int n_in,
                              void* d_out, int out_size, void* d_ws, size_t ws_size,
                              hipStream_t stream) {
  const float* V    = (const float*)d_in[0];
  const float* mask = (const float*)d_in[1];
  const int*   sbeg = (const int*)d_in[2];
  const int*   send = (const int*)d_in[3];
  const int*   slen = (const int*)d_in[4];
  const float* W1 = (const float*)d_in[5];
  const float* B1 = (const float*)d_in[6];
  const float* W2 = (const float*)d_in[7];
  const float* B2 = (const float*)d_in[8];
  const float* W3 = (const float*)d_in[9];
  const float* B3 = (const float*)d_in[10];
  float* out = (float*)d_out;
  int* ws_idx = (int*)d_ws;
  int* ws_sl = ws_idx + B_ * KTOP;

  prep_kernel<<<2560, 256, 0, stream>>>(W1, W2);
  init_kernel<<<240, 256, 0, stream>>>();
  gemm_kernel<1><<<1920, 256, 0, stream>>>(V, B1, nullptr);
  gemm_kernel<2><<<1920, 256, 0, stream>>>(nullptr, B2, W3);
  finalize_kernel<<<240, 256, 0, stream>>>(mask, B3, out);
  topk_kernel<<<B_, 256, 0, stream>>>(out, slen, out, ws_idx, ws_sl);
  gather_kernel<<<B_ * KTOP, 192, 0, stream>>>(V, sbeg, send, out, ws_idx);
  masks_kernel<<<(B_ * KTOP * KTOP + 255) / 256, 256, 0, stream>>>(out, ws_sl);
}